// Round 1
// baseline (526.963 us; speedup 1.0000x reference)
//
#include <hip/hip_runtime.h>
#include <cstdint>
#include <cstddef>

#define NF 128
#define NH 64

// ---------------- build kernels ----------------

__global__ __launch_bounds__(256) void zero_kernel(int* __restrict__ p, int n) {
  int i = blockIdx.x * 256 + threadIdx.x;
  if (i < n) p[i] = 0;
}

__global__ __launch_bounds__(256) void count_kernel(const int* __restrict__ ei, int E,
                                                    int* __restrict__ cnt) {
  int e = blockIdx.x * 256 + threadIdx.x;
  if (e < E) atomicAdd(&cnt[ei[E + e]], 1);
}

// per-1024-element block sums
__global__ __launch_bounds__(256) void partial_kernel(const int* __restrict__ cnt, int N,
                                                      int* __restrict__ part) {
  __shared__ int sd[256];
  int t = threadIdx.x;
  int idx = blockIdx.x * 1024 + t * 4;
  int s = 0;
#pragma unroll
  for (int j = 0; j < 4; ++j)
    if (idx + j < N) s += cnt[idx + j];
  sd[t] = s;
  __syncthreads();
  for (int off = 128; off > 0; off >>= 1) {
    if (t < off) sd[t] += sd[t + off];
    __syncthreads();
  }
  if (t == 0) part[blockIdx.x] = sd[0];
}

// exclusive-scan the block partials (NB <= 128), write total to rowptr[N]
__global__ __launch_bounds__(128) void scanp_kernel(int* __restrict__ part, int NB,
                                                    int* __restrict__ rowptrN) {
  __shared__ int s[128];
  int t = threadIdx.x;
  int v = (t < NB) ? part[t] : 0;
  s[t] = v;
  __syncthreads();
  for (int off = 1; off < 128; off <<= 1) {
    int add = (t >= off) ? s[t - off] : 0;
    __syncthreads();
    s[t] += add;
    __syncthreads();
  }
  if (t < NB) part[t] = s[t] - v;  // exclusive
  if (t == 0) rowptrN[0] = s[127];
}

// rowptr (exclusive scan of cnt) + dinv = rsqrt(deg) with deg = cnt + 1 (self-loop)
__global__ __launch_bounds__(256) void rowptr_kernel(const int* __restrict__ cnt,
                                                     const int* __restrict__ part,
                                                     int* __restrict__ rowptr,
                                                     float* __restrict__ dinv, int N) {
  __shared__ int s[256];
  int t = threadIdx.x;
  int idx = blockIdx.x * 1024 + t * 4;
  int c[4];
  int ts = 0;
#pragma unroll
  for (int j = 0; j < 4; ++j) {
    c[j] = (idx + j < N) ? cnt[idx + j] : 0;
    ts += c[j];
  }
  s[t] = ts;
  __syncthreads();
  for (int off = 1; off < 256; off <<= 1) {
    int add = (t >= off) ? s[t - off] : 0;
    __syncthreads();
    s[t] += add;
    __syncthreads();
  }
  int run = s[t] - ts + part[blockIdx.x];
#pragma unroll
  for (int j = 0; j < 4; ++j) {
    if (idx + j < N) {
      rowptr[idx + j] = run;
      dinv[idx + j] = rsqrtf((float)(c[j] + 1));
    }
    run += c[j];
  }
}

__global__ __launch_bounds__(256) void fill_kernel(const int* __restrict__ ei, int E,
                                                   const int* __restrict__ rowptr,
                                                   int* __restrict__ cnt2,
                                                   const float* __restrict__ dinv,
                                                   int* __restrict__ col,
                                                   float* __restrict__ wgt) {
  int e = blockIdx.x * 256 + threadIdx.x;
  if (e >= E) return;
  int s = ei[e];
  int d = ei[E + e];
  int pos = rowptr[d] + atomicAdd(&cnt2[d], 1);
  col[pos] = s;
  wgt[pos] = dinv[s] * dinv[d];
}

// ---------------- compute kernels ----------------

// H[n][64] = sum_k X[n][k] * W[k][64]; wave = 8 nodes, lane = out feature
template <int K>
__global__ __launch_bounds__(256) void gemm_kernel(const float* __restrict__ X,
                                                   const float* __restrict__ W,
                                                   float* __restrict__ H, int N) {
  __shared__ float Ws[K * 64];
  for (int i = threadIdx.x; i < K * 64; i += 256) Ws[i] = W[i];
  __syncthreads();
  int lane = threadIdx.x & 63;
  int base = (blockIdx.x * 4 + (threadIdx.x >> 6)) * 8;
  base = __builtin_amdgcn_readfirstlane(base);
  if (base >= N) return;
  float acc[8] = {0.f, 0.f, 0.f, 0.f, 0.f, 0.f, 0.f, 0.f};
  const float* xp = X + (size_t)base * K;
#pragma unroll 4
  for (int k = 0; k < K; ++k) {
    float wv = Ws[k * 64 + lane];
#pragma unroll
    for (int i = 0; i < 8; ++i)
      acc[i] = fmaf(xp[(size_t)i * K + k], wv, acc[i]);
  }
#pragma unroll
  for (int i = 0; i < 8; ++i) {
    int n = base + i;
    if (n < N) H[(size_t)n * 64 + lane] = acc[i];
  }
}

// wave = 1 node, lane = feature. CSR gather + bias + relu.
// FINAL=1: fuse 64->2 linear + log_softmax into epilogue.
template <int FINAL>
__global__ __launch_bounds__(256) void prop_kernel(
    const float* __restrict__ H, const int* __restrict__ rowptr,
    const int* __restrict__ col, const float* __restrict__ wgt,
    const float* __restrict__ dinv, const float* __restrict__ bias,
    const float* __restrict__ Wlin, const float* __restrict__ blin,
    float* __restrict__ out, int N) {
  int lane = threadIdx.x & 63;
  int n = blockIdx.x * 4 + (threadIdx.x >> 6);
  n = __builtin_amdgcn_readfirstlane(n);
  if (n >= N) return;
  int e0 = rowptr[n];
  int e1 = rowptr[n + 1];
  float di = dinv[n];
  float acc = H[(size_t)n * 64 + lane] * (di * di);  // self-loop
  int e = e0;
  for (; e + 4 <= e1; e += 4) {
    int s0 = col[e], s1 = col[e + 1], s2 = col[e + 2], s3 = col[e + 3];
    float w0 = wgt[e], w1 = wgt[e + 1], w2 = wgt[e + 2], w3 = wgt[e + 3];
    float h0 = H[(size_t)s0 * 64 + lane];
    float h1 = H[(size_t)s1 * 64 + lane];
    float h2 = H[(size_t)s2 * 64 + lane];
    float h3 = H[(size_t)s3 * 64 + lane];
    acc = fmaf(w0, h0, acc);
    acc = fmaf(w1, h1, acc);
    acc = fmaf(w2, h2, acc);
    acc = fmaf(w3, h3, acc);
  }
  for (; e < e1; ++e) acc = fmaf(wgt[e], H[(size_t)col[e] * 64 + lane], acc);
  float r = acc + bias[lane];
  r = r > 0.f ? r : 0.f;
  if (FINAL == 0) {
    out[(size_t)n * 64 + lane] = r;
  } else {
    float t0 = r * Wlin[lane * 2 + 0];
    float t1 = r * Wlin[lane * 2 + 1];
#pragma unroll
    for (int off = 32; off > 0; off >>= 1) {
      t0 += __shfl_xor(t0, off, 64);
      t1 += __shfl_xor(t1, off, 64);
    }
    if (lane == 0) {
      float l0 = t0 + blin[0];
      float l1 = t1 + blin[1];
      float m = fmaxf(l0, l1);
      float lz = m + logf(expf(l0 - m) + expf(l1 - m));
      out[(size_t)n * 2 + 0] = l0 - lz;
      out[(size_t)n * 2 + 1] = l1 - lz;
    }
  }
}

// ---------------- launcher ----------------

extern "C" void kernel_launch(void* const* d_in, const int* in_sizes, int n_in,
                              void* d_out, int out_size, void* d_ws, size_t ws_size,
                              hipStream_t stream) {
  const float* x  = (const float*)d_in[0];
  const int*   ei = (const int*)d_in[1];
  const float* W1 = (const float*)d_in[2];
  const float* b1 = (const float*)d_in[3];
  const float* W2 = (const float*)d_in[4];
  const float* b2 = (const float*)d_in[5];
  const float* W3 = (const float*)d_in[6];
  const float* b3 = (const float*)d_in[7];
  const float* Wl = (const float*)d_in[8];
  const float* bl = (const float*)d_in[9];
  float* out = (float*)d_out;

  const int N = in_sizes[0] / NF;  // 100000
  const int E = in_sizes[1] / 2;   // 1600000

  // workspace carve-up
  char* w = (char*)d_ws;
  size_t off = 0;
  auto alloc = [&](size_t bytes) {
    void* p = w + off;
    off += bytes;
    off = (off + 15) & ~(size_t)15;
    return p;
  };
  int*   cnt    = (int*)alloc((size_t)N * 4);
  int*   cnt2   = (int*)alloc((size_t)N * 4);
  int*   rowptr = (int*)alloc((size_t)(N + 1) * 4);
  int*   part   = (int*)alloc(256 * 4);
  float* dinv   = (float*)alloc((size_t)N * 4);
  int*   col    = (int*)alloc((size_t)E * 4);
  float* wgt    = (float*)alloc((size_t)E * 4);
  float* hA     = (float*)alloc((size_t)N * NH * 4);
  float* hB     = (float*)alloc((size_t)N * NH * 4);

  const int NB = (N + 1023) / 1024;  // 98 (<=128 required by scanp)

  hipLaunchKernelGGL(zero_kernel, dim3((2 * N + 255) / 256), dim3(256), 0, stream, cnt, 2 * N);
  hipLaunchKernelGGL(count_kernel, dim3((E + 255) / 256), dim3(256), 0, stream, ei, E, cnt);
  hipLaunchKernelGGL(partial_kernel, dim3(NB), dim3(256), 0, stream, cnt, N, part);
  hipLaunchKernelGGL(scanp_kernel, dim3(1), dim3(128), 0, stream, part, NB, rowptr + N);
  hipLaunchKernelGGL(rowptr_kernel, dim3(NB), dim3(256), 0, stream, cnt, part, rowptr, dinv, N);
  hipLaunchKernelGGL(fill_kernel, dim3((E + 255) / 256), dim3(256), 0, stream,
                     ei, E, rowptr, cnt2, dinv, col, wgt);

  hipLaunchKernelGGL(gemm_kernel<128>, dim3((N + 31) / 32), dim3(256), 0, stream, x, W1, hA, N);
  hipLaunchKernelGGL(prop_kernel<0>, dim3((N + 3) / 4), dim3(256), 0, stream,
                     hA, rowptr, col, wgt, dinv, b1, (const float*)nullptr,
                     (const float*)nullptr, hB, N);
  hipLaunchKernelGGL(gemm_kernel<64>, dim3((N + 31) / 32), dim3(256), 0, stream, hB, W2, hA, N);
  hipLaunchKernelGGL(prop_kernel<0>, dim3((N + 3) / 4), dim3(256), 0, stream,
                     hA, rowptr, col, wgt, dinv, b2, (const float*)nullptr,
                     (const float*)nullptr, hB, N);
  hipLaunchKernelGGL(gemm_kernel<64>, dim3((N + 31) / 32), dim3(256), 0, stream, hB, W3, hA, N);
  hipLaunchKernelGGL(prop_kernel<1>, dim3((N + 3) / 4), dim3(256), 0, stream,
                     hA, rowptr, col, wgt, dinv, b3, Wl, bl, out, N);
}

// Round 2
// 481.343 us; speedup vs baseline: 1.0948x; 1.0948x over previous
//
#include <hip/hip_runtime.h>
#include <cstdint>
#include <cstddef>

#define NF 128
#define NH 64

// ---------------- build kernels ----------------

__global__ __launch_bounds__(256) void zero_kernel(int* __restrict__ p, int n) {
  int i = blockIdx.x * 256 + threadIdx.x;
  if (i < n) p[i] = 0;
}

__global__ __launch_bounds__(256) void count_kernel(const int* __restrict__ ei, int E,
                                                    int* __restrict__ cnt) {
  int e = blockIdx.x * 256 + threadIdx.x;
  if (e < E) atomicAdd(&cnt[ei[E + e]], 1);
}

// per-1024-element block sums
__global__ __launch_bounds__(256) void partial_kernel(const int* __restrict__ cnt, int N,
                                                      int* __restrict__ part) {
  __shared__ int sd[256];
  int t = threadIdx.x;
  int idx = blockIdx.x * 1024 + t * 4;
  int s = 0;
#pragma unroll
  for (int j = 0; j < 4; ++j)
    if (idx + j < N) s += cnt[idx + j];
  sd[t] = s;
  __syncthreads();
  for (int off = 128; off > 0; off >>= 1) {
    if (t < off) sd[t] += sd[t + off];
    __syncthreads();
  }
  if (t == 0) part[blockIdx.x] = sd[0];
}

// exclusive-scan the block partials (NB <= 128), write total to rowptr[N]
__global__ __launch_bounds__(128) void scanp_kernel(int* __restrict__ part, int NB,
                                                    int* __restrict__ rowptrN) {
  __shared__ int s[128];
  int t = threadIdx.x;
  int v = (t < NB) ? part[t] : 0;
  s[t] = v;
  __syncthreads();
  for (int off = 1; off < 128; off <<= 1) {
    int add = (t >= off) ? s[t - off] : 0;
    __syncthreads();
    s[t] += add;
    __syncthreads();
  }
  if (t < NB) part[t] = s[t] - v;  // exclusive
  if (t == 0) rowptrN[0] = s[127];
}

// rowptr (exclusive scan of cnt) + dinv = rsqrt(deg) with deg = cnt + 1 (self-loop)
__global__ __launch_bounds__(256) void rowptr_kernel(const int* __restrict__ cnt,
                                                     const int* __restrict__ part,
                                                     int* __restrict__ rowptr,
                                                     float* __restrict__ dinv, int N) {
  __shared__ int s[256];
  int t = threadIdx.x;
  int idx = blockIdx.x * 1024 + t * 4;
  int c[4];
  int ts = 0;
#pragma unroll
  for (int j = 0; j < 4; ++j) {
    c[j] = (idx + j < N) ? cnt[idx + j] : 0;
    ts += c[j];
  }
  s[t] = ts;
  __syncthreads();
  for (int off = 1; off < 256; off <<= 1) {
    int add = (t >= off) ? s[t - off] : 0;
    __syncthreads();
    s[t] += add;
    __syncthreads();
  }
  int run = s[t] - ts + part[blockIdx.x];
#pragma unroll
  for (int j = 0; j < 4; ++j) {
    if (idx + j < N) {
      rowptr[idx + j] = run;
      dinv[idx + j] = rsqrtf((float)(c[j] + 1));
    }
    run += c[j];
  }
}

// scatter edges into CSR col array (weights recomputed in prop from dinv)
__global__ __launch_bounds__(256) void fill_kernel(const int* __restrict__ ei, int E,
                                                   const int* __restrict__ rowptr,
                                                   int* __restrict__ cnt2,
                                                   int* __restrict__ col) {
  int e = blockIdx.x * 256 + threadIdx.x;
  if (e >= E) return;
  int s = ei[e];
  int d = ei[E + e];
  int pos = rowptr[d] + atomicAdd(&cnt2[d], 1);
  col[pos] = s;
}

// ---------------- compute kernels ----------------

// H[n][64] = sum_k X[n][k] * W[k][64]
// Block = 64 nodes, 256 threads; K staged in 64-chunks:
//   XsT[64][68]  transposed X chunk (padded stride 68, 16B-aligned rows)
//   Ws[64*64]    W chunk
// Thread computes a 4(node)x4(feat) register tile: 2x ds_read_b128 + 16 FMA / k.
template <int K>
__global__ __launch_bounds__(256, 4) void gemm_kernel(const float* __restrict__ X,
                                                      const float* __restrict__ W,
                                                      float* __restrict__ H, int N) {
  __shared__ float XsT[64][68];
  __shared__ float Ws[64 * 64];
  const int tid = threadIdx.x;
  const int n0 = blockIdx.x * 64;
  const int tn = (tid >> 4) * 4;  // node offset within tile, 0..60
  const int tf = (tid & 15) * 4;  // feat offset, 0..60

  float acc[4][4];
#pragma unroll
  for (int i = 0; i < 4; ++i)
#pragma unroll
    for (int j = 0; j < 4; ++j) acc[i][j] = 0.f;

  for (int kt = 0; kt < K / 64; ++kt) {
    // stage W chunk [64][64] (linear copy, coalesced)
    {
      const float4* Wg = (const float4*)(W + (size_t)kt * 64 * 64);
      float4* Wl = (float4*)Ws;
#pragma unroll
      for (int j = 0; j < 4; ++j) Wl[tid + j * 256] = Wg[tid + j * 256];
    }
    // stage X chunk transposed: read float4 along k, scatter to XsT[k][n]
#pragma unroll
    for (int j = 0; j < 4; ++j) {
      int idx = tid + j * 256;  // 0..1023
      int n = idx >> 4;         // 0..63
      int kq = idx & 15;        // float4 index along the 64-wide k chunk
      float4 v = make_float4(0.f, 0.f, 0.f, 0.f);
      if (n0 + n < N)
        v = *(const float4*)(X + (size_t)(n0 + n) * K + kt * 64 + kq * 4);
      XsT[kq * 4 + 0][n] = v.x;
      XsT[kq * 4 + 1][n] = v.y;
      XsT[kq * 4 + 2][n] = v.z;
      XsT[kq * 4 + 3][n] = v.w;
    }
    __syncthreads();
#pragma unroll 8
    for (int k = 0; k < 64; ++k) {
      float4 xv = *(const float4*)(&XsT[k][tn]);
      float4 wv = *(const float4*)(&Ws[k * 64 + tf]);
      acc[0][0] = fmaf(xv.x, wv.x, acc[0][0]);
      acc[0][1] = fmaf(xv.x, wv.y, acc[0][1]);
      acc[0][2] = fmaf(xv.x, wv.z, acc[0][2]);
      acc[0][3] = fmaf(xv.x, wv.w, acc[0][3]);
      acc[1][0] = fmaf(xv.y, wv.x, acc[1][0]);
      acc[1][1] = fmaf(xv.y, wv.y, acc[1][1]);
      acc[1][2] = fmaf(xv.y, wv.z, acc[1][2]);
      acc[1][3] = fmaf(xv.y, wv.w, acc[1][3]);
      acc[2][0] = fmaf(xv.z, wv.x, acc[2][0]);
      acc[2][1] = fmaf(xv.z, wv.y, acc[2][1]);
      acc[2][2] = fmaf(xv.z, wv.z, acc[2][2]);
      acc[2][3] = fmaf(xv.z, wv.w, acc[2][3]);
      acc[3][0] = fmaf(xv.w, wv.x, acc[3][0]);
      acc[3][1] = fmaf(xv.w, wv.y, acc[3][1]);
      acc[3][2] = fmaf(xv.w, wv.z, acc[3][2]);
      acc[3][3] = fmaf(xv.w, wv.w, acc[3][3]);
    }
    __syncthreads();
  }
  // epilogue: each thread writes 4 nodes x float4
#pragma unroll
  for (int i = 0; i < 4; ++i) {
    int n = n0 + tn + i;
    if (n < N)
      *(float4*)(H + (size_t)n * 64 + tf) =
          make_float4(acc[i][0], acc[i][1], acc[i][2], acc[i][3]);
  }
}

// wave = 1 node, lane = feature. CSR gather + bias + relu.
// Edge weight recomputed as dinv[src]*dinv[dst] (broadcast loads from L2).
// FINAL=1: fuse 64->2 linear + log_softmax into epilogue.
template <int FINAL>
__global__ __launch_bounds__(256) void prop_kernel(
    const float* __restrict__ H, const int* __restrict__ rowptr,
    const int* __restrict__ col, const float* __restrict__ dinv,
    const float* __restrict__ bias, const float* __restrict__ Wlin,
    const float* __restrict__ blin, float* __restrict__ out, int N) {
  int lane = threadIdx.x & 63;
  int n = blockIdx.x * 4 + (threadIdx.x >> 6);
  n = __builtin_amdgcn_readfirstlane(n);
  if (n >= N) return;
  int e0 = rowptr[n];
  int e1 = rowptr[n + 1];
  float di = dinv[n];
  float acc = H[(size_t)n * 64 + lane] * (di * di);  // self-loop
  int e = e0;
  for (; e + 4 <= e1; e += 4) {
    int s0 = col[e], s1 = col[e + 1], s2 = col[e + 2], s3 = col[e + 3];
    float w0 = dinv[s0] * di, w1 = dinv[s1] * di;
    float w2 = dinv[s2] * di, w3 = dinv[s3] * di;
    float h0 = H[(size_t)s0 * 64 + lane];
    float h1 = H[(size_t)s1 * 64 + lane];
    float h2 = H[(size_t)s2 * 64 + lane];
    float h3 = H[(size_t)s3 * 64 + lane];
    acc = fmaf(w0, h0, acc);
    acc = fmaf(w1, h1, acc);
    acc = fmaf(w2, h2, acc);
    acc = fmaf(w3, h3, acc);
  }
  for (; e < e1; ++e) {
    int s = col[e];
    acc = fmaf(dinv[s] * di, H[(size_t)s * 64 + lane], acc);
  }
  float r = acc + bias[lane];
  r = r > 0.f ? r : 0.f;
  if (FINAL == 0) {
    out[(size_t)n * 64 + lane] = r;
  } else {
    float t0 = r * Wlin[lane * 2 + 0];
    float t1 = r * Wlin[lane * 2 + 1];
#pragma unroll
    for (int off = 32; off > 0; off >>= 1) {
      t0 += __shfl_xor(t0, off, 64);
      t1 += __shfl_xor(t1, off, 64);
    }
    if (lane == 0) {
      float l0 = t0 + blin[0];
      float l1 = t1 + blin[1];
      float m = fmaxf(l0, l1);
      float lz = m + logf(expf(l0 - m) + expf(l1 - m));
      out[(size_t)n * 2 + 0] = l0 - lz;
      out[(size_t)n * 2 + 1] = l1 - lz;
    }
  }
}

// ---------------- launcher ----------------

extern "C" void kernel_launch(void* const* d_in, const int* in_sizes, int n_in,
                              void* d_out, int out_size, void* d_ws, size_t ws_size,
                              hipStream_t stream) {
  const float* x  = (const float*)d_in[0];
  const int*   ei = (const int*)d_in[1];
  const float* W1 = (const float*)d_in[2];
  const float* b1 = (const float*)d_in[3];
  const float* W2 = (const float*)d_in[4];
  const float* b2 = (const float*)d_in[5];
  const float* W3 = (const float*)d_in[6];
  const float* b3 = (const float*)d_in[7];
  const float* Wl = (const float*)d_in[8];
  const float* bl = (const float*)d_in[9];
  float* out = (float*)d_out;

  const int N = in_sizes[0] / NF;  // 100000
  const int E = in_sizes[1] / 2;   // 1600000

  // workspace carve-up
  char* w = (char*)d_ws;
  size_t off = 0;
  auto alloc = [&](size_t bytes) {
    void* p = w + off;
    off += bytes;
    off = (off + 15) & ~(size_t)15;
    return p;
  };
  int*   cnt    = (int*)alloc((size_t)N * 4);
  int*   cnt2   = (int*)alloc((size_t)N * 4);
  int*   rowptr = (int*)alloc((size_t)(N + 1) * 4);
  int*   part   = (int*)alloc(256 * 4);
  float* dinv   = (float*)alloc((size_t)N * 4);
  int*   col    = (int*)alloc((size_t)E * 4);
  float* hA     = (float*)alloc((size_t)N * NH * 4);
  float* hB     = (float*)alloc((size_t)N * NH * 4);

  const int NB = (N + 1023) / 1024;  // 98 (<=128 required by scanp)

  hipLaunchKernelGGL(zero_kernel, dim3((2 * N + 255) / 256), dim3(256), 0, stream, cnt, 2 * N);
  hipLaunchKernelGGL(count_kernel, dim3((E + 255) / 256), dim3(256), 0, stream, ei, E, cnt);
  hipLaunchKernelGGL(partial_kernel, dim3(NB), dim3(256), 0, stream, cnt, N, part);
  hipLaunchKernelGGL(scanp_kernel, dim3(1), dim3(128), 0, stream, part, NB, rowptr + N);
  hipLaunchKernelGGL(rowptr_kernel, dim3(NB), dim3(256), 0, stream, cnt, part, rowptr, dinv, N);
  hipLaunchKernelGGL(fill_kernel, dim3((E + 255) / 256), dim3(256), 0, stream,
                     ei, E, rowptr, cnt2, col);

  hipLaunchKernelGGL(gemm_kernel<128>, dim3((N + 63) / 64), dim3(256), 0, stream, x, W1, hA, N);
  hipLaunchKernelGGL(prop_kernel<0>, dim3((N + 3) / 4), dim3(256), 0, stream,
                     hA, rowptr, col, dinv, b1, (const float*)nullptr,
                     (const float*)nullptr, hB, N);
  hipLaunchKernelGGL(gemm_kernel<64>, dim3((N + 63) / 64), dim3(256), 0, stream, hB, W2, hA, N);
  hipLaunchKernelGGL(prop_kernel<0>, dim3((N + 3) / 4), dim3(256), 0, stream,
                     hA, rowptr, col, dinv, b2, (const float*)nullptr,
                     (const float*)nullptr, hB, N);
  hipLaunchKernelGGL(gemm_kernel<64>, dim3((N + 63) / 64), dim3(256), 0, stream, hB, W3, hA, N);
  hipLaunchKernelGGL(prop_kernel<1>, dim3((N + 3) / 4), dim3(256), 0, stream,
                     hA, rowptr, col, dinv, b3, Wl, bl, out, N);
}